// Round 4
// baseline (484.581 us; speedup 1.0000x reference)
//
#include <hip/hip_runtime.h>
#include <math.h>

// GraphAttention single-node aggregate, restructured:
//   w = kernel @ attn_neigh            (128)   -- prep kernel
//   x_t = x @ kernel                   (64)    -- prep kernel
//   s_i = X_i . w ; online softmax over N; acc = sum p_i * X_i (128)  -- main
//   out = 0.75 * ((acc/L) @ kernel) + 0.25 * x_t                      -- finalize
// attn_self drops out entirely (softmax shift invariance).
//
// R4: residency fix. R3's 1024 blocks @ 3-resident-blocks/CU ran as a full
// round + a 1/3-full round (+41 us). Now: TPB=256, grid=2048,
// __launch_bounds__(256,8) -> 8 blocks/CU, grid == capacity, no tail.
// Single softmax state + register prefetch keeps ~40 VGPR (<=64 so 8 waves/EU
// is actually granted) with one load always in flight per wave.

#define TPB 256          // 4 waves per block in main kernel
#define MAXBLK 2048      // grid = 8 blocks/CU * 256 CU
#define PART_STRIDE 136  // floats per block partial: [0]=m,[1]=l,[8..135]=acc
#define PART_BASE 256    // float offset in ws where partials start (0..127=w, 128..191=x_t)
#define FIN_TPB 512

__global__ __launch_bounds__(128) void gat_prep(
    const float* __restrict__ x, const float* __restrict__ kern,
    const float* __restrict__ attn_neigh, float* __restrict__ ws) {
  int t = threadIdx.x;  // 128 threads
  float s = 0.f;
#pragma unroll 8
  for (int c = 0; c < 64; ++c) s += kern[t * 64 + c] * attn_neigh[c];
  ws[t] = s;
  if (t < 64) {
    float s2 = 0.f;
#pragma unroll 8
    for (int j = 0; j < 128; ++j) s2 += x[j] * kern[j * 64 + t];
    ws[128 + t] = s2;
  }
}

__global__ __launch_bounds__(TPB, 8) void gat_main(
    const float4* __restrict__ X4, const float* __restrict__ ws,
    float* __restrict__ part, int N, int totalWaves) {
  const int lane = threadIdx.x & 63;
  const int half = lane >> 5;       // 0: even row of pair, 1: odd row
  const int hl = lane & 31;
  const int wid = threadIdx.x >> 6; // wave in block (0..3)
  const int gwave = blockIdx.x * (TPB / 64) + wid;

  const float4 wv = ((const float4*)ws)[hl];  // w fragment: features 4*hl..4*hl+3

  const int npairs = N >> 1;  // full pairs; odd row handled after the loop
  const int stride = totalWaves;

  float m = -INFINITY, l = 0.f;
  float ax = 0.f, ay = 0.f, az = 0.f, aw = 0.f;

  int p = gwave;
  float4 xv = make_float4(0.f, 0.f, 0.f, 0.f);
  if (p < npairs) xv = X4[(size_t)p * 64 + lane];  // wave-uniform branch

  for (; p + stride < npairs; p += stride) {
    // prefetch next chunk (unconditional: loop condition guarantees validity)
    const float4 xn = X4[(size_t)(p + stride) * 64 + lane];

    float s = xv.x * wv.x + xv.y * wv.y + xv.z * wv.z + xv.w * wv.w;
    s += __shfl_xor(s, 1);  s += __shfl_xor(s, 2);  s += __shfl_xor(s, 4);
    s += __shfl_xor(s, 8);  s += __shfl_xor(s, 16);
    const float mn = fmaxf(m, s);
    const float corr = __expf(m - mn);   // m=-inf -> corr=0 (safe)
    const float pw = __expf(s - mn);
    l = l * corr + pw;
    ax = ax * corr + pw * xv.x;  ay = ay * corr + pw * xv.y;
    az = az * corr + pw * xv.z;  aw = aw * corr + pw * xv.w;
    m = mn;

    xv = xn;
  }
  if (p < npairs) {  // last chunk (already loaded)
    float s = xv.x * wv.x + xv.y * wv.y + xv.z * wv.z + xv.w * wv.w;
    s += __shfl_xor(s, 1);  s += __shfl_xor(s, 2);  s += __shfl_xor(s, 4);
    s += __shfl_xor(s, 8);  s += __shfl_xor(s, 16);
    const float mn = fmaxf(m, s);
    const float corr = __expf(m - mn);
    const float pw = __expf(s - mn);
    l = l * corr + pw;
    ax = ax * corr + pw * xv.x;  ay = ay * corr + pw * xv.y;
    az = az * corr + pw * xv.z;  aw = aw * corr + pw * xv.w;
    m = mn;
  }

  // odd-N tail: one extra row, handled by gwave 0's lower half once
  if ((N & 1) && gwave == 0) {
    float4 tv = make_float4(0.f, 0.f, 0.f, 0.f);
    if (half == 0) tv = X4[(size_t)(N - 1) * 32 + hl];
    float s = tv.x * wv.x + tv.y * wv.y + tv.z * wv.z + tv.w * wv.w;
    s += __shfl_xor(s, 1);  s += __shfl_xor(s, 2);  s += __shfl_xor(s, 4);
    s += __shfl_xor(s, 8);  s += __shfl_xor(s, 16);
    if (half == 0) {
      const float mn = fmaxf(m, s);
      const float corr = __expf(m - mn);
      const float pw = __expf(s - mn);
      l = l * corr + pw;
      ax = ax * corr + pw * tv.x;  ay = ay * corr + pw * tv.y;
      az = az * corr + pw * tv.z;  aw = aw * corr + pw * tv.w;
      m = mn;
    }
  }

  // combine the two 32-lane halves of this wave
  const float m_o = __shfl_xor(m, 32);
  const float l_o = __shfl_xor(l, 32);
  const float axo = __shfl_xor(ax, 32);
  const float ayo = __shfl_xor(ay, 32);
  const float azo = __shfl_xor(az, 32);
  const float awo = __shfl_xor(aw, 32);
  const float M2 = fmaxf(m, m_o);
  const float c0 = (m == -INFINITY) ? 0.f : __expf(m - M2);
  const float c1 = (m_o == -INFINITY) ? 0.f : __expf(m_o - M2);
  const float l2 = l * c0 + l_o * c1;
  const float bx = ax * c0 + axo * c1;
  const float by = ay * c0 + ayo * c1;
  const float bz = az * c0 + azo * c1;
  const float bw = aw * c0 + awo * c1;

  __shared__ float sm[TPB / 64];
  __shared__ float sl[TPB / 64];
  __shared__ float sacc[TPB / 64][128];
  if (lane < 32) {
    sacc[wid][hl * 4 + 0] = bx;
    sacc[wid][hl * 4 + 1] = by;
    sacc[wid][hl * 4 + 2] = bz;
    sacc[wid][hl * 4 + 3] = bw;
    if (hl == 0) { sm[wid] = M2; sl[wid] = l2; }
  }
  __syncthreads();

  if (threadIdx.x < 32) {
    float Mb = -INFINITY;
#pragma unroll
    for (int w2 = 0; w2 < TPB / 64; ++w2) Mb = fmaxf(Mb, sm[w2]);
    float Lb = 0.f, fx = 0.f, fy = 0.f, fz = 0.f, fw = 0.f;
#pragma unroll
    for (int w2 = 0; w2 < TPB / 64; ++w2) {
      const float sc = (sm[w2] == -INFINITY) ? 0.f : __expf(sm[w2] - Mb);
      Lb += sc * sl[w2];
      fx += sc * sacc[w2][hl * 4 + 0];
      fy += sc * sacc[w2][hl * 4 + 1];
      fz += sc * sacc[w2][hl * 4 + 2];
      fw += sc * sacc[w2][hl * 4 + 3];
    }
    float* pb = part + (size_t)blockIdx.x * PART_STRIDE;
    if (hl == 0) { pb[0] = Mb; pb[1] = Lb; }
    float4 v = make_float4(fx, fy, fz, fw);
    ((float4*)(pb + 8))[hl] = v;  // 16B-aligned: PART_BASE/STRIDE multiples of 8
  }
}

__global__ __launch_bounds__(FIN_TPB) void gat_fin(
    const float* __restrict__ kern, const float* __restrict__ ws,
    float* __restrict__ out, int nblk) {
  __shared__ float scale[MAXBLK];
  __shared__ float red[FIN_TPB];
  __shared__ float fpart[4][128];
  __shared__ float feats[128];
  const int t = threadIdx.x;  // 512 threads
  const float* part = ws + PART_BASE;

  // global max M over block partials
  float m = -INFINITY;
  for (int b = t; b < nblk; b += FIN_TPB) m = fmaxf(m, part[(size_t)b * PART_STRIDE]);
  red[t] = m;
  __syncthreads();
  for (int s = FIN_TPB / 2; s > 0; s >>= 1) {
    if (t < s) red[t] = fmaxf(red[t], red[t + s]);
    __syncthreads();
  }
  const float M = red[0];
  __syncthreads();

  // scales + global L
  float lp = 0.f;
  for (int b = t; b < nblk; b += FIN_TPB) {
    const float mb = part[(size_t)b * PART_STRIDE];
    const float sc = (mb == -INFINITY) ? 0.f : __expf(mb - M);
    scale[b] = sc;
    lp += sc * part[(size_t)b * PART_STRIDE + 1];
  }
  red[t] = lp;
  __syncthreads();
  for (int s = FIN_TPB / 2; s > 0; s >>= 1) {
    if (t < s) red[t] += red[t + s];
    __syncthreads();
  }
  const float L = red[0];
  __syncthreads();

  // feats[j] = (1/L) * sum_b scale_b * acc_b[j]  — 4-way split over blocks
  {
    const int j = t & 127;      // feature
    const int q = t >> 7;       // quarter 0..3
    float f = 0.f;
    for (int b = q; b < nblk; b += 4) f += scale[b] * part[(size_t)b * PART_STRIDE + 8 + j];
    fpart[q][j] = f;
  }
  __syncthreads();
  if (t < 128) feats[t] = (fpart[0][t] + fpart[1][t] + fpart[2][t] + fpart[3][t]) / L;
  __syncthreads();

  // out[c] = 0.75 * (feats @ kernel)[c] + 0.25 * x_t[c]
  if (t < 64) {
    float s = 0.f;
#pragma unroll 8
    for (int j = 0; j < 128; ++j) s += feats[j] * kern[j * 64 + t];
    out[t] = 0.75f * s + 0.25f * ws[128 + t];
  }
}

extern "C" void kernel_launch(void* const* d_in, const int* in_sizes, int n_in,
                              void* d_out, int out_size, void* d_ws, size_t ws_size,
                              hipStream_t stream) {
  const float* x          = (const float*)d_in[0];
  const float* X          = (const float*)d_in[1];
  const float* kern       = (const float*)d_in[2];
  // d_in[3] = attn_self: unused — softmax is invariant to the constant shift.
  const float* attn_neigh = (const float*)d_in[4];
  float* ws  = (float*)d_ws;
  float* out = (float*)d_out;

  const int N = in_sizes[1] / 128;

  // Guard: prep region + block partials must fit in ws (always true at 1 GB).
  int nblk = MAXBLK;
  const size_t availF = ws_size / 4;
  if (availF < (size_t)PART_BASE + (size_t)MAXBLK * PART_STRIDE) {
    long cap = ((long)availF - PART_BASE) / PART_STRIDE;
    nblk = (cap < 1) ? 1 : (int)cap;
  }
  const int totalWaves = nblk * (TPB / 64);

  gat_prep<<<1, 128, 0, stream>>>(x, kern, attn_neigh, ws);
  gat_main<<<nblk, TPB, 0, stream>>>((const float4*)X, ws, ws + PART_BASE,
                                     N, totalWaves);
  gat_fin<<<1, FIN_TPB, 0, stream>>>(kern, ws, out, nblk);
}

// Round 6
// 396.530 us; speedup vs baseline: 1.2221x; 1.2221x over previous
//
#include <hip/hip_runtime.h>
#include <math.h>

// GraphAttention single-node aggregate, restructured:
//   w = kernel @ attn_neigh            (128)   -- prep kernel
//   x_t = x @ kernel                   (64)    -- prep kernel
//   s_i = X_i . w ; online softmax over N; acc = sum p_i * X_i (128)  -- main
//   out = 0.75 * ((acc/L) @ kernel) + 0.25 * x_t                      -- finalize
// attn_self drops out entirely (softmax shift invariance).
//
// R5 (resubmitted R6 after infra timeout): R2 geometry (512 blocks x 512 thr,
// all resident, 16 waves/CU) after R3/R4 showed "more blocks" regresses
// (scheduling tail + VGPR cap spills + nblk-linear finalize cost). Changes:
//  - 2-deep rotating load pipeline in main (consume at k what was issued at
//    k-2): 16 waves/CU x 2KB in flight = 32KB/CU > ~18KB BDP -> latency hidden.
//  - launch_bounds(512,4): 128-VGPR cap, kernel ~45 VGPR, no spill risk.
//  - SoA partials (m[] | l[] | acc[j*nblk+b]) so ALL finalize reads coalesce;
//    feats reduction is wave-per-feature with shfl -> fin ~10us, nblk-indep.

#define TPB 512          // 8 waves per block in main kernel
#define NBLK 512         // grid: 2 blocks/CU * 256 CU, all resident
#define PART_BASE 256    // float offset in ws: 0..127=w, 128..191=x_t
#define FIN_TPB 512

__global__ __launch_bounds__(128) void gat_prep(
    const float* __restrict__ x, const float* __restrict__ kern,
    const float* __restrict__ attn_neigh, float* __restrict__ ws) {
  int t = threadIdx.x;  // 128 threads
  float s = 0.f;
#pragma unroll 8
  for (int c = 0; c < 64; ++c) s += kern[t * 64 + c] * attn_neigh[c];
  ws[t] = s;
  if (t < 64) {
    float s2 = 0.f;
#pragma unroll 8
    for (int j = 0; j < 128; ++j) s2 += x[j] * kern[j * 64 + t];
    ws[128 + t] = s2;
  }
}

__global__ __launch_bounds__(TPB, 4) void gat_main(
    const float4* __restrict__ X4, const float* __restrict__ ws,
    float* __restrict__ part, int N, int nblk) {
  const int lane = threadIdx.x & 63;
  const int half = lane >> 5;       // 0: even row of pair, 1: odd row
  const int hl = lane & 31;
  const int wid = threadIdx.x >> 6; // wave in block (0..7)
  const int gwave = blockIdx.x * (TPB / 64) + wid;
  const int stride = nblk * (TPB / 64);

  const float4 wv = ((const float4*)ws)[hl];  // w fragment: features 4*hl..4*hl+3

  const int npairs = N >> 1;  // full pairs; odd row handled after the loop

  float m = -INFINITY, l = 0.f;
  float ax = 0.f, ay = 0.f, az = 0.f, aw = 0.f;

#define PROC(XV)                                                            \
  {                                                                         \
    float s = (XV).x * wv.x + (XV).y * wv.y + (XV).z * wv.z + (XV).w * wv.w;\
    s += __shfl_xor(s, 1);  s += __shfl_xor(s, 2);  s += __shfl_xor(s, 4);  \
    s += __shfl_xor(s, 8);  s += __shfl_xor(s, 16);                         \
    const float mn = fmaxf(m, s);                                           \
    const float corr = __expf(m - mn); /* m=-inf -> 0, safe */              \
    const float pw = __expf(s - mn);                                        \
    l = l * corr + pw;                                                      \
    ax = ax * corr + pw * (XV).x;  ay = ay * corr + pw * (XV).y;            \
    az = az * corr + pw * (XV).z;  aw = aw * corr + pw * (XV).w;            \
    m = mn;                                                                 \
  }

  // 2-deep rotating pipeline: consume chunk p while p+stride and p+2*stride
  // loads are in flight.
  int p = gwave;
  float4 x0 = make_float4(0.f, 0.f, 0.f, 0.f);
  float4 x1 = make_float4(0.f, 0.f, 0.f, 0.f);
  if (p < npairs) x0 = X4[(size_t)p * 64 + lane];                 // uniform branch
  if (p + stride < npairs) x1 = X4[(size_t)(p + stride) * 64 + lane];
  for (; p + 2 * stride < npairs; p += stride) {
    const float4 xn = X4[(size_t)(p + 2 * stride) * 64 + lane];   // unconditional
    PROC(x0);
    x0 = x1;
    x1 = xn;
  }
  if (p < npairs) PROC(x0);
  if (p + stride < npairs) PROC(x1);

  // odd-N tail: one extra row, handled by gwave 0's lower half once
  if ((N & 1) && gwave == 0) {
    float4 tv = make_float4(0.f, 0.f, 0.f, 0.f);
    if (half == 0) tv = X4[(size_t)(N - 1) * 32 + hl];
    float s = tv.x * wv.x + tv.y * wv.y + tv.z * wv.z + tv.w * wv.w;
    s += __shfl_xor(s, 1);  s += __shfl_xor(s, 2);  s += __shfl_xor(s, 4);
    s += __shfl_xor(s, 8);  s += __shfl_xor(s, 16);
    if (half == 0) {
      const float mn = fmaxf(m, s);
      const float corr = __expf(m - mn);
      const float pw = __expf(s - mn);
      l = l * corr + pw;
      ax = ax * corr + pw * tv.x;  ay = ay * corr + pw * tv.y;
      az = az * corr + pw * tv.z;  aw = aw * corr + pw * tv.w;
      m = mn;
    }
  }
#undef PROC

  // combine the two 32-lane halves of this wave
  const float m_o = __shfl_xor(m, 32);
  const float l_o = __shfl_xor(l, 32);
  const float axo = __shfl_xor(ax, 32);
  const float ayo = __shfl_xor(ay, 32);
  const float azo = __shfl_xor(az, 32);
  const float awo = __shfl_xor(aw, 32);
  const float M2 = fmaxf(m, m_o);
  const float c0 = (m == -INFINITY) ? 0.f : __expf(m - M2);
  const float c1 = (m_o == -INFINITY) ? 0.f : __expf(m_o - M2);
  const float l2 = l * c0 + l_o * c1;
  const float bx = ax * c0 + axo * c1;
  const float by = ay * c0 + ayo * c1;
  const float bz = az * c0 + azo * c1;
  const float bw = aw * c0 + awo * c1;

  __shared__ float sm[TPB / 64];
  __shared__ float sl[TPB / 64];
  __shared__ float sacc[TPB / 64][128];
  if (lane < 32) {
    sacc[wid][hl * 4 + 0] = bx;
    sacc[wid][hl * 4 + 1] = by;
    sacc[wid][hl * 4 + 2] = bz;
    sacc[wid][hl * 4 + 3] = bw;
    if (hl == 0) { sm[wid] = M2; sl[wid] = l2; }
  }
  __syncthreads();

  // first 32 threads combine the block's 8 wave-partials; SoA write-out:
  //   part layout: m[nblk] | l[nblk] | acc[j*nblk + b]
  if (threadIdx.x < 32) {
    float Mb = -INFINITY;
#pragma unroll
    for (int w2 = 0; w2 < TPB / 64; ++w2) Mb = fmaxf(Mb, sm[w2]);
    float Lb = 0.f, fx = 0.f, fy = 0.f, fz = 0.f, fw = 0.f;
#pragma unroll
    for (int w2 = 0; w2 < TPB / 64; ++w2) {
      const float sc = (sm[w2] == -INFINITY) ? 0.f : __expf(sm[w2] - Mb);
      Lb += sc * sl[w2];
      fx += sc * sacc[w2][hl * 4 + 0];
      fy += sc * sacc[w2][hl * 4 + 1];
      fz += sc * sacc[w2][hl * 4 + 2];
      fw += sc * sacc[w2][hl * 4 + 3];
    }
    const int b = blockIdx.x;
    float* part_m = part;
    float* part_l = part + nblk;
    float* part_a = part + 2 * nblk;
    if (hl == 0) { part_m[b] = Mb; part_l[b] = Lb; }
    part_a[(size_t)(4 * hl + 0) * nblk + b] = fx;
    part_a[(size_t)(4 * hl + 1) * nblk + b] = fy;
    part_a[(size_t)(4 * hl + 2) * nblk + b] = fz;
    part_a[(size_t)(4 * hl + 3) * nblk + b] = fw;
  }
}

__global__ __launch_bounds__(FIN_TPB) void gat_fin(
    const float* __restrict__ kern, const float* __restrict__ ws,
    float* __restrict__ out, int nblk) {
  __shared__ float scale[NBLK];
  __shared__ float red[FIN_TPB];
  __shared__ float feats[128];
  const int t = threadIdx.x;  // 512 threads = 8 waves
  const int lane = t & 63;
  const int wid = t >> 6;
  const float* part_m = ws + PART_BASE;
  const float* part_l = part_m + nblk;
  const float* part_a = part_l + nblk;

  // global max M over block partials (coalesced: m[] contiguous)
  float m = -INFINITY;
  for (int b = t; b < nblk; b += FIN_TPB) m = fmaxf(m, part_m[b]);
  red[t] = m;
  __syncthreads();
  for (int s = FIN_TPB / 2; s > 0; s >>= 1) {
    if (t < s) red[t] = fmaxf(red[t], red[t + s]);
    __syncthreads();
  }
  const float M = red[0];
  __syncthreads();

  // scales + global L (coalesced)
  float lp = 0.f;
  for (int b = t; b < nblk; b += FIN_TPB) {
    const float mb = part_m[b];
    const float sc = (mb == -INFINITY) ? 0.f : __expf(mb - M);
    scale[b] = sc;
    lp += sc * part_l[b];
  }
  red[t] = lp;
  __syncthreads();
  for (int s = FIN_TPB / 2; s > 0; s >>= 1) {
    if (t < s) red[t] += red[t + s];
    __syncthreads();
  }
  const float L = red[0];
  __syncthreads();

  // feats[j] = (1/L) * sum_b scale[b] * acc[j*nblk+b]
  // wave w handles features j = w*16 .. w*16+15; lanes stride b (coalesced).
  for (int jj = 0; jj < 16; ++jj) {
    const int j = wid * 16 + jj;
    float f = 0.f;
    for (int b = lane; b < nblk; b += 64) f += scale[b] * part_a[(size_t)j * nblk + b];
    f += __shfl_xor(f, 1);  f += __shfl_xor(f, 2);  f += __shfl_xor(f, 4);
    f += __shfl_xor(f, 8);  f += __shfl_xor(f, 16); f += __shfl_xor(f, 32);
    if (lane == 0) feats[j] = f / L;
  }
  __syncthreads();

  // out[c] = 0.75 * (feats @ kernel)[c] + 0.25 * x_t[c]
  if (t < 64) {
    float s = 0.f;
#pragma unroll 8
    for (int j = 0; j < 128; ++j) s += feats[j] * kern[j * 64 + t];
    out[t] = 0.75f * s + 0.25f * ws[128 + t];
  }
}

extern "C" void kernel_launch(void* const* d_in, const int* in_sizes, int n_in,
                              void* d_out, int out_size, void* d_ws, size_t ws_size,
                              hipStream_t stream) {
  const float* x          = (const float*)d_in[0];
  const float* X          = (const float*)d_in[1];
  const float* kern       = (const float*)d_in[2];
  // d_in[3] = attn_self: unused — softmax is invariant to the constant shift.
  const float* attn_neigh = (const float*)d_in[4];
  float* ws  = (float*)d_ws;
  float* out = (float*)d_out;

  const int N = in_sizes[1] / 128;

  // ws need: PART_BASE + nblk*(2 + 128) floats  (= ~261 KB at nblk=512)
  int nblk = NBLK;
  const size_t availF = ws_size / 4;
  if (availF < (size_t)PART_BASE + (size_t)NBLK * 130) {
    long cap = ((long)availF - PART_BASE) / 130;
    nblk = (cap < 1) ? 1 : (int)cap;
  }

  gat_prep<<<1, 128, 0, stream>>>(x, kern, attn_neigh, ws);
  gat_main<<<nblk, TPB, 0, stream>>>((const float4*)X, ws, ws + PART_BASE,
                                     N, nblk);
  gat_fin<<<1, FIN_TPB, 0, stream>>>(kern, ws, out, nblk);
}